// Round 1
// baseline (595.645 us; speedup 1.0000x reference)
//
#include <hip/hip_runtime.h>
#include <hip/hip_fp16.h>

// ---- problem constants ----
#define SQ   1024          // sequence length
#define DM   1024          // d_model
#define NH   16            // heads
#define HD   64            // head dim
#define BSZ  4             // batch
#define MROW 4096          // BSZ*SQ

typedef _Float16 f16;
typedef f16  f16x8 __attribute__((ext_vector_type(8)));
typedef float f32x4 __attribute__((ext_vector_type(4)));

#define MFMA16(a,b,c) __builtin_amdgcn_mfma_f32_16x16x32_f16(a,b,c,0,0,0)

// ws layout in halves:
//  [0)            xin16: query,key,value fp16   3 * 4194304
//  [12582912)     w16:   Wq,Wk,Wv fp16          3 * 1048576
//  [15728640)     er16:  Er fp16                16*2049*64 = 2098176
//  [17826816)     qkv16: q,k,v fp16 [b,h,s,64]  3 * 4194304
//  total 30409728 halves = 60.8 MB
#define XIN16OFF  0
#define W16OFF    12582912
#define ER16OFF   15728640
#define QKV16OFF  17826816

// ---------------- kernel 1: fp32 -> fp16 conversion ----------------
__global__ __launch_bounds__(256) void cvt_all(
    const float* __restrict__ q, const float* __restrict__ k, const float* __restrict__ v,
    const float* __restrict__ wq, const float* __restrict__ wk, const float* __restrict__ wv,
    const float* __restrict__ er, f16* __restrict__ ws)
{
    int z = blockIdx.z;
    const float* src; f16* dst; int n;
    if (z < 3)      { src = (z==0)?q:((z==1)?k:v);    dst = ws + (size_t)z*4194304;              n = 4194304; }
    else if (z < 6) { src = (z==3)?wq:((z==4)?wk:wv); dst = ws + W16OFF + (size_t)(z-3)*1048576; n = 1048576; }
    else            { src = er;                        dst = ws + ER16OFF;                        n = 2098176; }
    int idx = (blockIdx.x*256 + threadIdx.x) * 8;
    if (idx >= n) return;
    float4 a = *(const float4*)&src[idx];
    float4 b = *(const float4*)&src[idx+4];
    f16x8 o;
    o[0]=(f16)a.x; o[1]=(f16)a.y; o[2]=(f16)a.z; o[3]=(f16)a.w;
    o[4]=(f16)b.x; o[5]=(f16)b.y; o[6]=(f16)b.z; o[7]=(f16)b.w;
    *(f16x8*)&dst[idx] = o;
}

// ---------------- kernel 2: projection GEMMs  C = X @ W^T + b ----------------
// grid (N/64=16, M/64=64, 3);  64x64 tile, BK=32, 4 waves in 2x2, fp16 MFMA fp32 acc.
// Output layout: qkv16[z][b][h][s][d]  (z: 0=q,1=k,2=v)
__global__ __launch_bounds__(256) void proj_gemm(
    f16* __restrict__ ws, const float* __restrict__ bq,
    const float* __restrict__ bk, const float* __restrict__ bv)
{
    int z = blockIdx.z;
    const f16* X = ws + XIN16OFF + (size_t)z*4194304;
    const f16* W = ws + W16OFF   + (size_t)z*1048576;
    const float* bias = (z==0)?bq:((z==1)?bk:bv);
    f16* dst = ws + QKV16OFF + (size_t)z*4194304;

    int n0 = blockIdx.x * 64, m0 = blockIdx.y * 64;
    int tid = threadIdx.x, lane = tid & 63, w = tid >> 6;
    int wm = (w >> 1) * 32, wn = (w & 1) * 32;

    __shared__ f16 As[64*40];   // row stride 40 halves (80B): 16B-aligned, conflict-light
    __shared__ f16 Bs[64*40];

    f32x4 acc[2][2];
    #pragma unroll
    for (int a=0;a<2;++a) for (int b=0;b<2;++b) { acc[a][b][0]=0.f;acc[a][b][1]=0.f;acc[a][b][2]=0.f;acc[a][b][3]=0.f; }

    int row = tid >> 2, kc = (tid & 3) * 8;
    int fr = lane & 15, fk = (lane >> 4) << 3;

    for (int k0 = 0; k0 < 1024; k0 += 32) {
        __syncthreads();
        *(f16x8*)&As[row*40 + kc] = *(const f16x8*)&X[(size_t)(m0+row)*1024 + k0 + kc];
        *(f16x8*)&Bs[row*40 + kc] = *(const f16x8*)&W[(size_t)(n0+row)*1024 + k0 + kc];
        __syncthreads();
        f16x8 af[2], bf[2];
        af[0] = *(const f16x8*)&As[(wm +      fr)*40 + fk];
        af[1] = *(const f16x8*)&As[(wm + 16 + fr)*40 + fk];
        bf[0] = *(const f16x8*)&Bs[(wn +      fr)*40 + fk];
        bf[1] = *(const f16x8*)&Bs[(wn + 16 + fr)*40 + fk];
        #pragma unroll
        for (int a=0;a<2;++a)
            #pragma unroll
            for (int b=0;b<2;++b)
                acc[a][b] = MFMA16(af[a], bf[b], acc[a][b]);
    }

    int coln = lane & 15, rq = (lane >> 4) << 2;
    #pragma unroll
    for (int bb = 0; bb < 2; ++bb) {
        int j = n0 + wn + bb*16 + coln;
        int hh = j >> 6, dd = j & 63;
        float bsv = bias[j];
        #pragma unroll
        for (int a = 0; a < 2; ++a) {
            #pragma unroll
            for (int r = 0; r < 4; ++r) {
                int m = m0 + wm + a*16 + rq + r;
                int bidx = m >> 10, s = m & 1023;
                dst[((size_t)(bidx*16 + hh)*1024 + s)*64 + dd] = (f16)(acc[a][bb][r] + bsv);
            }
        }
    }
}

// ---------------- kernel 3: scores (QK^T + skewed Q·Er), softmax, write attn ----------------
// grid (64 s-blocks, 64 bh).  Block = 16 Q-rows x 1024 cols; wave w owns cols [w*256,(w+1)*256).
// Srel[s,t] = QEr[s, 1023+t-s]; per 16x16 tile, two Er n-tiles + ds_bpermute diagonal gather.
__global__ __launch_bounds__(256) void attn_kernel(
    const f16* __restrict__ ws, float* __restrict__ attn)
{
    const f16* qkv = ws + QKV16OFF;
    const f16* er  = ws + ER16OFF;
    int bh = blockIdx.y;
    int h  = bh & 15;
    int s0 = blockIdx.x << 4;
    int tid = threadIdx.x, lane = tid & 63, w = tid >> 6;

    const f16* qb = qkv + (size_t)bh * 65536;
    const f16* kb = qkv + 4194304 + (size_t)bh * 65536;
    const f16* E  = er + (size_t)h * 2049 * 64;

    int fr = lane & 15, fk = (lane >> 4) << 3;
    f16x8 qf0 = *(const f16x8*)&qb[(s0+fr)*64 + fk];
    f16x8 qf1 = *(const f16x8*)&qb[(s0+fr)*64 + fk + 32];

    int tbase = w << 8;
    f32x4 sc[16];
    int l0 = 1008 + tbase - s0;                     // window base for first tile
    f16x8 e0a = *(const f16x8*)&E[(size_t)(l0+fr)*64 + fk];
    f16x8 e0b = *(const f16x8*)&E[(size_t)(l0+fr)*64 + fk + 32];

    #pragma unroll
    for (int i = 0; i < 16; ++i) {
        int t0 = tbase + (i << 4);
        f16x8 kf0 = *(const f16x8*)&kb[(t0+fr)*64 + fk];
        f16x8 kf1 = *(const f16x8*)&kb[(t0+fr)*64 + fk + 32];
        f32x4 c; c[0]=0.f;c[1]=0.f;c[2]=0.f;c[3]=0.f;
        c = MFMA16(qf0, kf0, c);
        c = MFMA16(qf1, kf1, c);

        int l1 = l0 + 16;
        f16x8 e1a = *(const f16x8*)&E[(size_t)(l1+fr)*64 + fk];
        f16x8 e1b = *(const f16x8*)&E[(size_t)(l1+fr)*64 + fk + 32];
        f32x4 r0; r0[0]=0.f;r0[1]=0.f;r0[2]=0.f;r0[3]=0.f;
        f32x4 r1; r1[0]=0.f;r1[1]=0.f;r1[2]=0.f;r1[3]=0.f;
        r0 = MFMA16(qf0, e0a, r0); r0 = MFMA16(qf1, e0b, r0);
        r1 = MFMA16(qf0, e1a, r1); r1 = MFMA16(qf1, e1b, r1);

        // gather rel along diagonals: score(shat, that) needs R[shat, jj], jj = that - shat + 15
        #pragma unroll
        for (int r = 0; r < 4; ++r) {
            int shat = ((lane >> 4) << 2) + r;
            int jj = (lane & 15) - shat + 15;               // [0,30]
            int addr = ((lane & 48) | (jj & 15)) << 2;      // src lane * 4
            float g0 = __int_as_float(__builtin_amdgcn_ds_bpermute(addr, __float_as_int(r0[r])));
            float g1 = __int_as_float(__builtin_amdgcn_ds_bpermute(addr, __float_as_int(r1[r])));
            c[r] = (c[r] + ((jj < 16) ? g0 : g1)) * 0.125f; // /sqrt(64)
        }
        sc[i] = c;
        e0a = e1a; e0b = e1b; l0 = l1;
    }

    // ---- softmax over full 1024 cols ----
    __shared__ float red[16][4];
    float mx[4];
    #pragma unroll
    for (int r = 0; r < 4; ++r) {
        float m = sc[0][r];
        #pragma unroll
        for (int i = 1; i < 16; ++i) m = fmaxf(m, sc[i][r]);
        m = fmaxf(m, __shfl_xor(m, 1));
        m = fmaxf(m, __shfl_xor(m, 2));
        m = fmaxf(m, __shfl_xor(m, 4));
        m = fmaxf(m, __shfl_xor(m, 8));
        mx[r] = m;
    }
    if ((lane & 15) == 0) {
        #pragma unroll
        for (int r = 0; r < 4; ++r) red[((lane>>4)<<2)+r][w] = mx[r];
    }
    __syncthreads();
    #pragma unroll
    for (int r = 0; r < 4; ++r) {
        int rw = ((lane>>4)<<2)+r;
        mx[r] = fmaxf(fmaxf(red[rw][0], red[rw][1]), fmaxf(red[rw][2], red[rw][3]));
    }
    __syncthreads();
    float sm[4];
    #pragma unroll
    for (int r = 0; r < 4; ++r) {
        float s = 0.f;
        #pragma unroll
        for (int i = 0; i < 16; ++i) { float e = __expf(sc[i][r] - mx[r]); sc[i][r] = e; s += e; }
        s += __shfl_xor(s, 1); s += __shfl_xor(s, 2);
        s += __shfl_xor(s, 4); s += __shfl_xor(s, 8);
        sm[r] = s;
    }
    if ((lane & 15) == 0) {
        #pragma unroll
        for (int r = 0; r < 4; ++r) red[((lane>>4)<<2)+r][w] = sm[r];
    }
    __syncthreads();
    float inv[4];
    #pragma unroll
    for (int r = 0; r < 4; ++r) {
        int rw = ((lane>>4)<<2)+r;
        inv[r] = 1.f / (red[rw][0] + red[rw][1] + red[rw][2] + red[rw][3]);
    }

    float* outb = attn + ((size_t)bh * 1024 + s0) * 1024;
    #pragma unroll
    for (int i = 0; i < 16; ++i) {
        int t = tbase + (i << 4) + (lane & 15);
        #pragma unroll
        for (int r = 0; r < 4; ++r) {
            int rw = ((lane>>4)<<2)+r;
            outb[(size_t)rw * 1024 + t] = sc[i][r] * inv[r];
        }
    }
}

// ---------------- kernel 4: out = attn @ v ----------------
// grid (16 s-blocks of 64, 64 bh). Wave w: rows [s0+16w, s0+16w+16), all 64 d-cols.
// attn (fp32, from d_out) is A; v transposed to LDS gives B-frags.
// attn scaled x512 into fp16 to stay clear of fp16 denormals; /512 in epilogue.
__global__ __launch_bounds__(256) void pv_kernel(
    const float* __restrict__ attn, const f16* __restrict__ ws, float* __restrict__ out)
{
    const f16* vbase = ws + QKV16OFF + 2*4194304;
    int bh = blockIdx.y, h = bh & 15, b = bh >> 4;
    int s0 = blockIdx.x << 6;
    int tid = threadIdx.x, lane = tid & 63, w = tid >> 6;
    const f16* v = vbase + (size_t)bh * 65536;
    const float* arow = attn + ((size_t)bh * 1024 + s0 + (w<<4)) * 1024;

    __shared__ f16 vt[64*40];   // vT[d][t-chunk of 32], row stride 40 halves
    f32x4 acc[4];
    #pragma unroll
    for (int nb=0;nb<4;++nb) { acc[nb][0]=0.f;acc[nb][1]=0.f;acc[nb][2]=0.f;acc[nb][3]=0.f; }

    int fr = lane & 15, fk = (lane >> 4) << 3;
    int tt = tid >> 3, dd = (tid & 7) << 3;

    for (int t0 = 0; t0 < 1024; t0 += 32) {
        __syncthreads();
        f16x8 vv = *(const f16x8*)&v[(size_t)(t0+tt)*64 + dd];
        #pragma unroll
        for (int j = 0; j < 8; ++j) vt[(dd+j)*40 + tt] = vv[j];
        __syncthreads();

        float4 a0 = *(const float4*)&arow[(size_t)fr*1024 + t0 + fk];
        float4 a1 = *(const float4*)&arow[(size_t)fr*1024 + t0 + fk + 4];
        f16x8 af;
        af[0]=(f16)(a0.x*512.f); af[1]=(f16)(a0.y*512.f); af[2]=(f16)(a0.z*512.f); af[3]=(f16)(a0.w*512.f);
        af[4]=(f16)(a1.x*512.f); af[5]=(f16)(a1.y*512.f); af[6]=(f16)(a1.z*512.f); af[7]=(f16)(a1.w*512.f);

        #pragma unroll
        for (int nb = 0; nb < 4; ++nb) {
            f16x8 bf = *(const f16x8*)&vt[((nb<<4)+fr)*40 + fk];
            acc[nb] = MFMA16(af, bf, acc[nb]);
        }
    }

    float* ob = out + ((size_t)b * 1024 + s0 + (w<<4)) * 1024 + h*64;
    int col = lane & 15;
    #pragma unroll
    for (int nb = 0; nb < 4; ++nb) {
        #pragma unroll
        for (int r = 0; r < 4; ++r) {
            int rw = ((lane>>4)<<2) + r;
            ob[(size_t)rw*1024 + (nb<<4) + col] = acc[nb][r] * (1.f/512.f);
        }
    }
}

extern "C" void kernel_launch(void* const* d_in, const int* in_sizes, int n_in,
                              void* d_out, int out_size, void* d_ws, size_t ws_size,
                              hipStream_t stream) {
    const float* query = (const float*)d_in[0];
    const float* key   = (const float*)d_in[1];
    const float* value = (const float*)d_in[2];
    const float* Wq    = (const float*)d_in[3];
    const float* bq    = (const float*)d_in[4];
    const float* Wk    = (const float*)d_in[5];
    const float* bk    = (const float*)d_in[6];
    const float* Wv    = (const float*)d_in[7];
    const float* bv    = (const float*)d_in[8];
    const float* Er    = (const float*)d_in[9];

    f16*   ws   = (f16*)d_ws;
    float* out  = (float*)d_out;            // 4,194,304 floats
    float* attn = out + 4194304;            // 67,108,864 floats

    cvt_all  <<<dim3(2048, 1, 7), 256, 0, stream>>>(query, key, value, Wq, Wk, Wv, Er, ws);
    proj_gemm<<<dim3(16, 64, 3),  256, 0, stream>>>(ws, bq, bk, bv);
    attn_kernel<<<dim3(64, 64),   256, 0, stream>>>(ws, attn);
    pv_kernel<<<dim3(16, 64),     256, 0, stream>>>(attn, ws, out);
}

// Round 2
// 561.758 us; speedup vs baseline: 1.0603x; 1.0603x over previous
//
#include <hip/hip_runtime.h>
#include <hip/hip_fp16.h>

// ---- problem constants ----
#define SQ   1024
#define DM   1024
#define NH   16
#define HD   64
#define BSZ  4

typedef _Float16 f16;
typedef f16  f16x8 __attribute__((ext_vector_type(8)));
typedef float f32x4 __attribute__((ext_vector_type(4)));

#define MFMA16(a,b,c) __builtin_amdgcn_mfma_f32_16x16x32_f16(a,b,c,0,0,0)

// async global->LDS, 16B per lane (dest = wave-uniform base + lane*16; no padding!)
#define GLOAD_LDS(g, l) __builtin_amdgcn_global_load_lds( \
    (const __attribute__((address_space(1))) void*)(g), \
    (__attribute__((address_space(3))) void*)(l), 16, 0, 0)

// ws layout in halves:
//  [0)            xin16: query,key,value fp16   3 * 4194304
//  [12582912)     w16:   Wq,Wk,Wv fp16          3 * 1048576
//  [15728640)     er16:  Er fp16                16*2049*64 = 2098176
//  [17826816)     qkv16: q,k,v fp16 [b,h,s,64]  3 * 4194304
//  [30409728)     vt16:  v^T fp16 [b,h,64,s]    4194304
#define XIN16OFF  0
#define W16OFF    12582912
#define ER16OFF   15728640
#define QKV16OFF  17826816
#define VTOFF     30409728

// ---------------- kernel 1: fp32 -> fp16 conversion ----------------
__global__ __launch_bounds__(256) void cvt_all(
    const float* __restrict__ q, const float* __restrict__ k, const float* __restrict__ v,
    const float* __restrict__ wq, const float* __restrict__ wk, const float* __restrict__ wv,
    const float* __restrict__ er, f16* __restrict__ ws)
{
    int z = blockIdx.z;
    const float* src; f16* dst; int n;
    if (z < 3)      { src = (z==0)?q:((z==1)?k:v);    dst = ws + (size_t)z*4194304;              n = 4194304; }
    else if (z < 6) { src = (z==3)?wq:((z==4)?wk:wv); dst = ws + W16OFF + (size_t)(z-3)*1048576; n = 1048576; }
    else            { src = er;                        dst = ws + ER16OFF;                        n = 2098176; }
    int idx = (blockIdx.x*256 + threadIdx.x) * 8;
    if (idx >= n) return;
    float4 a = *(const float4*)&src[idx];
    float4 b = *(const float4*)&src[idx+4];
    f16x8 o;
    o[0]=(f16)a.x; o[1]=(f16)a.y; o[2]=(f16)a.z; o[3]=(f16)a.w;
    o[4]=(f16)b.x; o[5]=(f16)b.y; o[6]=(f16)b.z; o[7]=(f16)b.w;
    *(f16x8*)&dst[idx] = o;
}

// ---------------- kernel 2: projection GEMMs  C = X @ W^T + b ----------------
// 128x128 tile, BK=32, 4 waves 2x2 (64x64 each, 4x4 MFMA acc), global_load_lds 16B.
// Output: qkv16[z][b][h][s][d]
__global__ __launch_bounds__(256) void proj_gemm(
    f16* __restrict__ ws, const float* __restrict__ bq,
    const float* __restrict__ bk, const float* __restrict__ bv)
{
    int z = blockIdx.z;
    const f16* X = ws + XIN16OFF + (size_t)z*4194304;
    const f16* W = ws + W16OFF   + (size_t)z*1048576;
    const float* bias = (z==0)?bq:((z==1)?bk:bv);
    f16* dst = ws + QKV16OFF + (size_t)z*4194304;

    int n0 = blockIdx.x * 128, m0 = blockIdx.y * 128;
    int tid = threadIdx.x, lane = tid & 63, w = tid >> 6;
    int wm = (w >> 1) * 64, wn = (w & 1) * 64;

    __shared__ f16 As[128*32];   // no pad: global_load_lds dest is lane-contiguous
    __shared__ f16 Bs[128*32];

    f32x4 acc[4][4];
    #pragma unroll
    for (int a=0;a<4;++a)
        #pragma unroll
        for (int b=0;b<4;++b) { acc[a][b][0]=0.f;acc[a][b][1]=0.f;acc[a][b][2]=0.f;acc[a][b][3]=0.f; }

    int srow0 = tid >> 2, srow1 = srow0 + 64, skc = (tid & 3) * 8;
    int fr = lane & 15, fk = (lane >> 4) << 3;

    for (int k0 = 0; k0 < 1024; k0 += 32) {
        __syncthreads();
        GLOAD_LDS(&X[(size_t)(m0+srow0)*1024 + k0 + skc], &As[srow0*32 + skc]);
        GLOAD_LDS(&X[(size_t)(m0+srow1)*1024 + k0 + skc], &As[srow1*32 + skc]);
        GLOAD_LDS(&W[(size_t)(n0+srow0)*1024 + k0 + skc], &Bs[srow0*32 + skc]);
        GLOAD_LDS(&W[(size_t)(n0+srow1)*1024 + k0 + skc], &Bs[srow1*32 + skc]);
        __syncthreads();   // compiler drains vmcnt before s_barrier
        f16x8 af[4], bf[4];
        #pragma unroll
        for (int a=0;a<4;++a) af[a] = *(const f16x8*)&As[(wm + a*16 + fr)*32 + fk];
        #pragma unroll
        for (int b=0;b<4;++b) bf[b] = *(const f16x8*)&Bs[(wn + b*16 + fr)*32 + fk];
        #pragma unroll
        for (int a=0;a<4;++a)
            #pragma unroll
            for (int b=0;b<4;++b)
                acc[a][b] = MFMA16(af[a], bf[b], acc[a][b]);
    }

    int coln = lane & 15, rq = (lane >> 4) << 2;
    #pragma unroll
    for (int tb = 0; tb < 4; ++tb) {
        int j = n0 + wn + tb*16 + coln;
        int hh = j >> 6, dd = j & 63;
        float bsv = bias[j];
        #pragma unroll
        for (int ta = 0; ta < 4; ++ta) {
            #pragma unroll
            for (int r = 0; r < 4; ++r) {
                int m = m0 + wm + ta*16 + rq + r;
                int bidx = m >> 10, s = m & 1023;
                dst[((size_t)(bidx*16 + hh)*1024 + s)*64 + dd] = (f16)(acc[ta][tb][r] + bsv);
            }
        }
    }
}

// ---------------- kernel 3: transpose v -> vT [bh][d][s] ----------------
__global__ __launch_bounds__(256) void transpose_v(f16* __restrict__ ws)
{
    const f16* v = ws + QKV16OFF + 2*4194304 + (size_t)blockIdx.y*65536;
    f16* o       = ws + VTOFF               + (size_t)blockIdx.y*65536;
    int s0 = blockIdx.x << 6;
    __shared__ f16 t[64][72];
    int tid = threadIdx.x;
    int r = tid >> 2, c = (tid & 3) << 4;
    f16x8 a = *(const f16x8*)&v[(size_t)(s0+r)*64 + c];
    f16x8 b = *(const f16x8*)&v[(size_t)(s0+r)*64 + c + 8];
    #pragma unroll
    for (int j = 0; j < 8; ++j) { t[r][c+j] = a[j]; t[r][c+8+j] = b[j]; }
    __syncthreads();
    int dr = tid >> 2, sc0 = (tid & 3) << 4;
    f16x8 o1, o2;
    #pragma unroll
    for (int j = 0; j < 8; ++j) { o1[j] = t[sc0+j][dr]; o2[j] = t[sc0+8+j][dr]; }
    *(f16x8*)&o[(size_t)dr*1024 + s0 + sc0]     = o1;
    *(f16x8*)&o[(size_t)dr*1024 + s0 + sc0 + 8] = o2;
}

// ---------------- kernel 4: fused scores + softmax + attn-write + PV ----------------
// grid (64 s-blocks of 16 rows, 64 bh). 4 waves, wave w owns t-cols [w*256,(w+1)*256).
__global__ __launch_bounds__(256) void attn_pv(
    const f16* __restrict__ ws, float* __restrict__ attn, float* __restrict__ out)
{
    const f16* qkv = ws + QKV16OFF;
    const f16* er  = ws + ER16OFF;
    int bh = blockIdx.y, h = bh & 15, b = bh >> 4;
    int s0 = blockIdx.x << 4;
    int tid = threadIdx.x, lane = tid & 63, w = tid >> 6;

    const f16* qb  = qkv + (size_t)bh * 65536;
    const f16* kb  = qkv + 4194304 + (size_t)bh * 65536;
    const f16* vtb = ws + VTOFF + (size_t)bh * 65536;
    const f16* E   = er + (size_t)h * 2049 * 64;

    // LDS: P16[w][16][264] f16 (33792 B), overlaid after PV by Ored[w][16][64] f32
    __shared__ __align__(16) f16 lds_pool[4*16*264];
    __shared__ float red[16][4];
    __shared__ float invs[16];
    f16* P16 = lds_pool + w * (16*264);

    int fr = lane & 15, fk = (lane >> 4) << 3;
    f16x8 qf0 = *(const f16x8*)&qb[(s0+fr)*64 + fk];
    f16x8 qf1 = *(const f16x8*)&qb[(s0+fr)*64 + fk + 32];

    int tbase = w << 8;
    f32x4 sc[16];
    int l0 = 1008 + tbase - s0;
    f16x8 e0a = *(const f16x8*)&E[(size_t)(l0+fr)*64 + fk];
    f16x8 e0b = *(const f16x8*)&E[(size_t)(l0+fr)*64 + fk + 32];

    #pragma unroll
    for (int i = 0; i < 16; ++i) {
        int t0 = tbase + (i << 4);
        f16x8 kf0 = *(const f16x8*)&kb[(t0+fr)*64 + fk];
        f16x8 kf1 = *(const f16x8*)&kb[(t0+fr)*64 + fk + 32];
        f32x4 c; c[0]=0.f;c[1]=0.f;c[2]=0.f;c[3]=0.f;
        c = MFMA16(qf0, kf0, c);
        c = MFMA16(qf1, kf1, c);

        int l1 = l0 + 16;
        f16x8 e1a = *(const f16x8*)&E[(size_t)(l1+fr)*64 + fk];
        f16x8 e1b = *(const f16x8*)&E[(size_t)(l1+fr)*64 + fk + 32];
        f32x4 r0; r0[0]=0.f;r0[1]=0.f;r0[2]=0.f;r0[3]=0.f;
        f32x4 r1; r1[0]=0.f;r1[1]=0.f;r1[2]=0.f;r1[3]=0.f;
        r0 = MFMA16(qf0, e0a, r0); r0 = MFMA16(qf1, e0b, r0);
        r1 = MFMA16(qf0, e1a, r1); r1 = MFMA16(qf1, e1b, r1);

        #pragma unroll
        for (int r = 0; r < 4; ++r) {
            int shat = ((lane >> 4) << 2) + r;
            int jj = (lane & 15) - shat + 15;               // [0,30]
            int addr = ((lane & 48) | (jj & 15)) << 2;
            float g0 = __int_as_float(__builtin_amdgcn_ds_bpermute(addr, __float_as_int(r0[r])));
            float g1 = __int_as_float(__builtin_amdgcn_ds_bpermute(addr, __float_as_int(r1[r])));
            c[r] = (c[r] + ((jj < 16) ? g0 : g1)) * 0.125f;
        }
        sc[i] = c;
        e0a = e1a; e0b = e1b; l0 = l1;
    }

    // ---- softmax (block-wide over 1024 cols) ----
    float mx[4];
    #pragma unroll
    for (int r = 0; r < 4; ++r) {
        float m = sc[0][r];
        #pragma unroll
        for (int i = 1; i < 16; ++i) m = fmaxf(m, sc[i][r]);
        m = fmaxf(m, __shfl_xor(m, 1));
        m = fmaxf(m, __shfl_xor(m, 2));
        m = fmaxf(m, __shfl_xor(m, 4));
        m = fmaxf(m, __shfl_xor(m, 8));
        mx[r] = m;
    }
    if ((lane & 15) == 0) {
        #pragma unroll
        for (int r = 0; r < 4; ++r) red[((lane>>4)<<2)+r][w] = mx[r];
    }
    __syncthreads();
    #pragma unroll
    for (int r = 0; r < 4; ++r) {
        int rw = ((lane>>4)<<2)+r;
        mx[r] = fmaxf(fmaxf(red[rw][0], red[rw][1]), fmaxf(red[rw][2], red[rw][3]));
    }
    __syncthreads();
    float sm[4];
    #pragma unroll
    for (int r = 0; r < 4; ++r) {
        int rw = ((lane>>4)<<2)+r;
        float s = 0.f;
        #pragma unroll
        for (int i = 0; i < 16; ++i) {
            float e = __expf(sc[i][r] - mx[r]);
            s += e;
            P16[rw*264 + (i<<4) + (lane & 15)] = (f16)e;   // unnormalized exp, in (~e^-20, 1]
        }
        s += __shfl_xor(s, 1); s += __shfl_xor(s, 2);
        s += __shfl_xor(s, 4); s += __shfl_xor(s, 8);
        sm[r] = s;
    }
    if ((lane & 15) == 0) {
        #pragma unroll
        for (int r = 0; r < 4; ++r) red[((lane>>4)<<2)+r][w] = sm[r];
    }
    __syncthreads();
    if (w == 0 && (lane & 15) == 0) {
        #pragma unroll
        for (int r = 0; r < 4; ++r) {
            int rw = ((lane>>4)<<2)+r;
            invs[rw] = 1.f / (red[rw][0] + red[rw][1] + red[rw][2] + red[rw][3]);
        }
    }
    __syncthreads();   // P16 + invs complete, visible block-wide

    // ---- attn write: coalesced float4 from LDS ----
    {
        float* outb = attn + ((size_t)bh * 1024 + s0) * 1024;
        int arow = tid >> 4;
        int ac0  = (tid & 15) << 2;
        float iv = invs[arow];
        #pragma unroll
        for (int it = 0; it < 16; ++it) {
            int col = ac0 + it*64;
            const f16* p = &lds_pool[(col >> 8)*(16*264) + arow*264 + (col & 255)];
            float4 o4;
            o4.x = (float)p[0] * iv; o4.y = (float)p[1] * iv;
            o4.z = (float)p[2] * iv; o4.w = (float)p[3] * iv;
            *(float4*)&outb[(size_t)arow*1024 + col] = o4;
        }
    }

    // ---- PV: O_partial[16x64] = P_w[16x256] @ V[256x64]  (A from LDS, B = vT global) ----
    f32x4 oacc[4];
    #pragma unroll
    for (int nb=0;nb<4;++nb) { oacc[nb][0]=0.f;oacc[nb][1]=0.f;oacc[nb][2]=0.f;oacc[nb][3]=0.f; }
    #pragma unroll
    for (int kc = 0; kc < 8; ++kc) {
        f16x8 af = *(const f16x8*)&P16[fr*264 + (kc<<5) + fk];
        #pragma unroll
        for (int nb = 0; nb < 4; ++nb) {
            f16x8 bf = *(const f16x8*)&vtb[(size_t)((nb<<4)+fr)*1024 + tbase + (kc<<5) + fk];
            oacc[nb] = MFMA16(af, bf, oacc[nb]);
        }
    }

    __syncthreads();   // everyone done reading P16 -> safe to overlay with Ored
    float* Ored = (float*)lds_pool;
    {
        float iv2[4];
        #pragma unroll
        for (int r = 0; r < 4; ++r) iv2[r] = invs[((lane>>4)<<2)+r];
        #pragma unroll
        for (int nb = 0; nb < 4; ++nb)
            #pragma unroll
            for (int r = 0; r < 4; ++r) {
                int rw = ((lane>>4)<<2)+r;
                Ored[w*1024 + rw*64 + (nb<<4) + (lane & 15)] = oacc[nb][r] * iv2[r];
            }
    }
    __syncthreads();
    {
        int frow = tid >> 4, fc = (tid & 15) << 2;
        float4 s4;
        s4.x = Ored[frow*64+fc+0] + Ored[1024+frow*64+fc+0] + Ored[2048+frow*64+fc+0] + Ored[3072+frow*64+fc+0];
        s4.y = Ored[frow*64+fc+1] + Ored[1024+frow*64+fc+1] + Ored[2048+frow*64+fc+1] + Ored[3072+frow*64+fc+1];
        s4.z = Ored[frow*64+fc+2] + Ored[1024+frow*64+fc+2] + Ored[2048+frow*64+fc+2] + Ored[3072+frow*64+fc+2];
        s4.w = Ored[frow*64+fc+3] + Ored[1024+frow*64+fc+3] + Ored[2048+frow*64+fc+3] + Ored[3072+frow*64+fc+3];
        *(float4*)&out[((size_t)b*1024 + s0 + frow)*1024 + h*64 + fc] = s4;
    }
}

extern "C" void kernel_launch(void* const* d_in, const int* in_sizes, int n_in,
                              void* d_out, int out_size, void* d_ws, size_t ws_size,
                              hipStream_t stream) {
    const float* query = (const float*)d_in[0];
    const float* key   = (const float*)d_in[1];
    const float* value = (const float*)d_in[2];
    const float* Wq    = (const float*)d_in[3];
    const float* bq    = (const float*)d_in[4];
    const float* Wk    = (const float*)d_in[5];
    const float* bk    = (const float*)d_in[6];
    const float* Wv    = (const float*)d_in[7];
    const float* bv    = (const float*)d_in[8];

    f16*   ws   = (f16*)d_ws;
    float* out  = (float*)d_out;            // 4,194,304 floats
    float* attn = out + 4194304;            // 67,108,864 floats

    cvt_all    <<<dim3(2048, 1, 7), 256, 0, stream>>>(query, key, value, Wq, Wk, Wv,
                                                      (const float*)d_in[9], ws);
    proj_gemm  <<<dim3(8, 32, 3),   256, 0, stream>>>(ws, bq, bk, bv);
    transpose_v<<<dim3(16, 64),     256, 0, stream>>>(ws);
    attn_pv    <<<dim3(64, 64),     256, 0, stream>>>(ws, attn, out);
}